// Round 5
// baseline (626.695 us; speedup 1.0000x reference)
//
#include <hip/hip_runtime.h>

#define TMAXV 100000
#define CHUNK 256
#define NCHUNK ((TMAXV + CHUNK - 1) / CHUNK)   // 391
#define NTPAD (NCHUNK * CHUNK)                  // 100096 padded slots
#define TILE 4096
#define RPT 16                                  // records per thread per tile
#define HSCALE 4096.0f                          // fixed-point scale for h
#define HINV (1.0f / 4096.0f)
#define THSHIFT 42                              // cm lives in bits [63:42] of packed

// Per-slot sums are EXACT integer adds (order-invariant), so the histogram can
// be built with native global atomics directly from the input stream:
//   sh_g[t]   += round(exp(x)*4096)                (u32, all records)
//   cmth_g[t] += (1<<42) | round(exp(x)*4096)      (u64, events: cm|th packed)
// Worst case per t: ~130 ties, hf<=2^22 -> th<=545M<2^42, cm<=130<2^22: no carry
// between fields; sh<=545M<2^32. Quantization: abs err <= 2^-13 per record,
// same encoding as rounds 3-4 (benched absmax 0.0).

// ---------------- block reduce helpers (blockDim.x == 256) ----------------
__device__ __forceinline__ float block_reduce_sum(float v, float* sdata) {
    int lane = threadIdx.x & 63;
    int wid  = threadIdx.x >> 6;
    #pragma unroll
    for (int off = 32; off > 0; off >>= 1)
        v += __shfl_down(v, off, 64);
    if (lane == 0) sdata[wid] = v;
    __syncthreads();
    if (wid == 0) {
        v = (lane < 4) ? sdata[lane] : 0.0f;
        v += __shfl_down(v, 2, 64);
        v += __shfl_down(v, 1, 64);
    }
    return v;  // valid in thread 0
}

__device__ __forceinline__ double block_reduce_sum_d(double v, double* sdata) {
    int lane = threadIdx.x & 63;
    int wid  = threadIdx.x >> 6;
    #pragma unroll
    for (int off = 32; off > 0; off >>= 1)
        v += __shfl_down(v, off, 64);
    if (lane == 0) sdata[wid] = v;
    __syncthreads();
    if (wid == 0) {
        v = (lane < 4) ? sdata[lane] : 0.0;
        v += __shfl_down(v, 2, 64);
        v += __shfl_down(v, 1, 64);
    }
    return v;  // valid in thread 0
}

// ================= FAST PATH =============================================

// ---- P1: one-pass direct histogram via native global integer atomics ----
__global__ __launch_bounds__(256, 8)
void hist_direct_kernel(const float* __restrict__ lh,
                        const int*   __restrict__ tgt,
                        const int*   __restrict__ ev,
                        unsigned* __restrict__ sh_g,
                        unsigned long long* __restrict__ cmth_g,
                        double* __restrict__ acc, int n) {
    __shared__ float sdata[4];
    int tid = threadIdx.x;
    float xl = 0.f;

    for (long long lo = (long long)blockIdx.x * TILE; lo < n;
         lo += (long long)gridDim.x * TILE) {
        if (lo + TILE <= n) {
            const int4*   tgt4 = (const int4*)(tgt + lo);
            const int4*   ev4  = (const int4*)(ev + lo);
            const float4* lh4  = (const float4*)(lh + lo);
            #pragma unroll
            for (int q = 0; q < RPT / 4; ++q) {
                int idx = q * 256 + tid;
                int4   t4 = tgt4[idx];
                int4   e4 = ev4[idx];
                float4 x4 = lh4[idx];
                {
                    unsigned hf = __float2uint_rn(__expf(x4.x) * HSCALE);
                    if (hf > 0x3FFFFFu) hf = 0x3FFFFFu;
                    atomicAdd(&sh_g[t4.x], hf);
                    if (e4.x & 1) { atomicAdd(&cmth_g[t4.x], (1ull << THSHIFT) | (unsigned long long)hf); xl += x4.x; }
                }
                {
                    unsigned hf = __float2uint_rn(__expf(x4.y) * HSCALE);
                    if (hf > 0x3FFFFFu) hf = 0x3FFFFFu;
                    atomicAdd(&sh_g[t4.y], hf);
                    if (e4.y & 1) { atomicAdd(&cmth_g[t4.y], (1ull << THSHIFT) | (unsigned long long)hf); xl += x4.y; }
                }
                {
                    unsigned hf = __float2uint_rn(__expf(x4.z) * HSCALE);
                    if (hf > 0x3FFFFFu) hf = 0x3FFFFFu;
                    atomicAdd(&sh_g[t4.z], hf);
                    if (e4.z & 1) { atomicAdd(&cmth_g[t4.z], (1ull << THSHIFT) | (unsigned long long)hf); xl += x4.z; }
                }
                {
                    unsigned hf = __float2uint_rn(__expf(x4.w) * HSCALE);
                    if (hf > 0x3FFFFFu) hf = 0x3FFFFFu;
                    atomicAdd(&sh_g[t4.w], hf);
                    if (e4.w & 1) { atomicAdd(&cmth_g[t4.w], (1ull << THSHIFT) | (unsigned long long)hf); xl += x4.w; }
                }
            }
        } else {
            for (long long i = lo + tid; i < n; i += 256) {
                int t = tgt[i]; int e = ev[i] & 1; float x = lh[i];
                unsigned hf = __float2uint_rn(__expf(x) * HSCALE);
                if (hf > 0x3FFFFFu) hf = 0x3FFFFFu;
                atomicAdd(&sh_g[t], hf);
                if (e) { atomicAdd(&cmth_g[t], (1ull << THSHIFT) | (unsigned long long)hf); xl += x; }
            }
        }
    }

    float rl = block_reduce_sum(xl, sdata);
    if (tid == 0) unsafeAtomicAdd(&acc[2], (double)rl);   // native f64 atomic
}

// ---- P2: per-chunk totals of sh (float, from exact u32 sums) ----
__global__ void chunk_sum_u32_kernel(const unsigned* __restrict__ sh_g,
                                     float* __restrict__ chunk_sum) {
    __shared__ float sdata[4];
    int i = blockIdx.x * CHUNK + threadIdx.x;
    float v = (i < TMAXV) ? (float)sh_g[i] * HINV : 0.0f;
    v = block_reduce_sum(v, sdata);
    if (threadIdx.x == 0) chunk_sum[blockIdx.x] = v;
}

// ---- P3: per-chunk suffix + Efron; last-done block finalizes the output
__global__ void pll_suffix_kernel(const unsigned* __restrict__ sh_g,
                                  const unsigned long long* __restrict__ cmth_g,
                                  const float* __restrict__ chunk_sum,
                                  double* __restrict__ acc,
                                  unsigned* __restrict__ done,
                                  float* __restrict__ out) {
    __shared__ float sf[CHUNK];
    __shared__ float sdata[4];
    __shared__ float sdata2[4];
    __shared__ double dsd[4];
    __shared__ double doff;
    int tid = threadIdx.x;
    int b   = blockIdx.x;
    int t   = b * CHUNK + tid;
    float sh = (t < TMAXV) ? (float)sh_g[t] * HINV : 0.0f;
    unsigned long long pk = (t < TMAXV) ? cmth_g[t] : 0ull;
    unsigned cmu = (unsigned)(pk >> THSHIFT);
    float th = (float)(pk & ((1ull << THSHIFT) - 1)) * HINV;
    sf[tid] = sh;
    __syncthreads();
    for (int off = 1; off < CHUNK; off <<= 1) {
        float add = (tid + off < CHUNK) ? sf[tid + off] : 0.0f;
        __syncthreads();
        sf[tid] += add;
        __syncthreads();
    }
    // strict-suffix over later chunks (double)
    double mysum = 0.0;
    for (int j = b + 1 + tid; j < NCHUNK; j += 256)
        mysum += (double)chunk_sum[j];
    double red = block_reduce_sum_d(mysum, dsd);
    if (tid == 0) doff = red;
    __syncthreads();
    double off_d = doff;

    float pll = 0.0f, inc = 0.0f;
    if (t < TMAXV && cmu > 0u) {
        float cm   = (float)cmu;
        float D    = (float)(off_d + (double)sf[tid]);
        int   mi   = (int)cmu;
        float step = th / cm;
        float s = 0.0f;
        for (int l = 0; l < mi; ++l)
            s += __logf(D - (float)l * step);
        pll = -s;            // log_nom handled globally via acc[2]
        inc = 1.0f;
    }
    float rp = block_reduce_sum(pll, sdata);
    __syncthreads();
    float ri = block_reduce_sum(inc, sdata2);
    if (tid == 0) {
        unsafeAtomicAdd(&acc[0], (double)rp);
        unsafeAtomicAdd(&acc[1], (double)ri);
        __threadfence();
        unsigned prev = __hip_atomic_fetch_add(done, 1u, __ATOMIC_ACQ_REL, __HIP_MEMORY_SCOPE_AGENT);
        if (prev == (unsigned)(gridDim.x - 1)) {
            double a0 = __hip_atomic_load(&acc[0], __ATOMIC_ACQUIRE, __HIP_MEMORY_SCOPE_AGENT);
            double a1 = __hip_atomic_load(&acc[1], __ATOMIC_RELAXED, __HIP_MEMORY_SCOPE_AGENT);
            double a2 = __hip_atomic_load(&acc[2], __ATOMIC_RELAXED, __HIP_MEMORY_SCOPE_AGENT);
            out[0] = (a1 > 0.0) ? (float)(-(a0 + a2) / a1) : 0.0f;
        }
    }
}

// ---- finalize (fallback path only) ----
__global__ void finalize_kernel(const double* __restrict__ acc,
                                float* __restrict__ out) {
    double cnt = acc[1];
    out[0] = (cnt > 0.0) ? (float)(-(acc[0] + acc[2]) / cnt) : 0.0f;
}

// ================= FALLBACK: round-1 global-atomic histogram ==============
__global__ void hist_kernel(const float* __restrict__ lh,
                            const int*   __restrict__ tgt,
                            const int*   __restrict__ ev,
                            float* __restrict__ sum_hz,
                            float* __restrict__ mcnt,
                            float* __restrict__ log_nom,
                            float* __restrict__ ties,
                            int n) {
    int i = blockIdx.x * blockDim.x + threadIdx.x;
    if (i >= n) return;
    float x = lh[i];
    int   t = tgt[i];
    int   e = ev[i];
    float h = __expf(x);
    unsafeAtomicAdd(&sum_hz[t], h);
    if (e) {
        unsafeAtomicAdd(&mcnt[t], 1.0f);
        unsafeAtomicAdd(&log_nom[t], x);
        unsafeAtomicAdd(&ties[t], h);
    }
}

__global__ void chunk_sum_kernel(const float* __restrict__ sum_hz,
                                 float* __restrict__ chunk_sum) {
    __shared__ float sdata[4];
    int i = blockIdx.x * CHUNK + threadIdx.x;
    float v = (i < TMAXV) ? sum_hz[i] : 0.0f;
    v = block_reduce_sum(v, sdata);
    if (threadIdx.x == 0) chunk_sum[blockIdx.x] = v;
}

__global__ void chunk_scan_kernel(const float* __restrict__ chunk_sum,
                                  double* __restrict__ chunk_off) {
    __shared__ double ds[512];
    int tid = threadIdx.x;
    double own = (tid < NCHUNK) ? (double)chunk_sum[tid] : 0.0;
    ds[tid] = own;
    __syncthreads();
    for (int off = 1; off < 512; off <<= 1) {
        double add = (tid + off < 512) ? ds[tid + off] : 0.0;
        __syncthreads();
        ds[tid] += add;
        __syncthreads();
    }
    if (tid < NCHUNK) chunk_off[tid] = ds[tid] - own;
}

__global__ void pll_kernel(const float* __restrict__ mcnt,
                           const float* __restrict__ log_nom,
                           const float* __restrict__ ties,
                           const float* __restrict__ sum_hz,
                           const double* __restrict__ chunk_off,
                           double* __restrict__ acc) {
    __shared__ float sf[CHUNK];
    __shared__ float sdata[4];
    __shared__ float sdata2[4];
    int tid = threadIdx.x;
    int t   = blockIdx.x * CHUNK + tid;
    float v = (t < TMAXV) ? sum_hz[t] : 0.0f;
    sf[tid] = v;
    __syncthreads();
    for (int off = 1; off < CHUNK; off <<= 1) {
        float add = (tid + off < CHUNK) ? sf[tid + off] : 0.0f;
        __syncthreads();
        sf[tid] += add;
        __syncthreads();
    }
    float pll = 0.0f, inc = 0.0f;
    if (t < TMAXV) {
        float mv = mcnt[t];
        if (mv > 0.5f) {
            float D    = (float)(chunk_off[blockIdx.x] + (double)sf[tid]);
            float T    = ties[t];
            int   mi   = (int)(mv + 0.5f);
            float step = T / mv;
            float s = 0.0f;
            for (int l = 0; l < mi; ++l)
                s += __logf(D - (float)l * step);
            pll = log_nom[t] - s;
            inc = 1.0f;
        }
    }
    float rp = block_reduce_sum(pll, sdata);
    __syncthreads();
    float ri = block_reduce_sum(inc, sdata2);
    if (threadIdx.x == 0) {
        atomicAdd(&acc[0], (double)rp);
        atomicAdd(&acc[1], (double)ri);
    }
}

// =========================================================================
extern "C" void kernel_launch(void* const* d_in, const int* in_sizes, int n_in,
                              void* d_out, int out_size, void* d_ws, size_t ws_size,
                              hipStream_t stream) {
    const float* lh  = (const float*)d_in[0];
    const int*   tgt = (const int*)d_in[1];
    const int*   ev  = (const int*)d_in[2];
    float*       out = (float*)d_out;
    int n  = in_sizes[0];
    int nt = (n + TILE - 1) / TILE;   // number of tiles

    char* ws = (char*)d_ws;
    size_t off = 0;
    auto take = [&](size_t bytes, size_t align) {
        off = (off + align - 1) & ~(align - 1);
        size_t r = off; off += bytes; return r;
    };
    // ---- zero region (single small memset) ----
    size_t o_acc   = take(32, 16);                        // 3 doubles used
    size_t o_done  = take(16, 16);                        // pll done counter
    size_t o_csum  = take((size_t)NCHUNK * 4, 16);        // chunk_sum (float)
    size_t o_shg   = take((size_t)NTPAD * 4, 16);         // per-t sum exp (u32 fx)
    size_t o_cmth  = take((size_t)NTPAD * 8, 16);         // per-t packed cm|th (u64)
    size_t need    = off;                                 // ~1.3 MB total

    if (ws_size >= need) {
        // ================= fast path =================
        double*             acc       = (double*)(ws + o_acc);
        unsigned*           done      = (unsigned*)(ws + o_done);
        float*              chunk_sum = (float*)(ws + o_csum);
        unsigned*           sh_g      = (unsigned*)(ws + o_shg);
        unsigned long long* cmth_g    = (unsigned long long*)(ws + o_cmth);

        hipMemsetAsync(ws, 0, need, stream);   // 1.3 MB

        int grid = nt < 2048 ? nt : 2048;
        hist_direct_kernel<<<grid, 256, 0, stream>>>(lh, tgt, ev, sh_g, cmth_g,
                                                     acc, n);
        chunk_sum_u32_kernel<<<NCHUNK, 256, 0, stream>>>(sh_g, chunk_sum);
        pll_suffix_kernel<<<NCHUNK, 256, 0, stream>>>(sh_g, cmth_g, chunk_sum,
                                                      acc, done, out);
    } else {
        // ================= fallback (round-1 style) =================
        size_t f = 0;
        auto ftake = [&](size_t bytes, size_t align) {
            f = (f + align - 1) & ~(align - 1);
            size_t r = f; f += bytes; return r;
        };
        size_t f_acc  = ftake(32, 16);
        size_t f_sum  = ftake((size_t)TMAXV * 4, 16);
        size_t f_m    = ftake((size_t)TMAXV * 4, 16);
        size_t f_ln   = ftake((size_t)TMAXV * 4, 16);
        size_t f_ties = ftake((size_t)TMAXV * 4, 16);
        size_t zb     = f;
        size_t f_csum = ftake((size_t)NCHUNK * 4, 16);
        size_t f_coff = ftake((size_t)NCHUNK * 8, 8);

        double* acc     = (double*)(ws + f_acc);
        float*  sum_hz  = (float*)(ws + f_sum);
        float*  mcnt    = (float*)(ws + f_m);
        float*  log_nom = (float*)(ws + f_ln);
        float*  ties    = (float*)(ws + f_ties);
        float*  chunk_sum = (float*)(ws + f_csum);
        double* chunk_off = (double*)(ws + f_coff);

        hipMemsetAsync(d_ws, 0, zb, stream);

        hist_kernel<<<(n + 255) / 256, 256, 0, stream>>>(lh, tgt, ev, sum_hz, mcnt, log_nom, ties, n);
        chunk_sum_kernel<<<NCHUNK, 256, 0, stream>>>(sum_hz, chunk_sum);
        chunk_scan_kernel<<<1, 512, 0, stream>>>(chunk_sum, chunk_off);
        pll_kernel<<<NCHUNK, 256, 0, stream>>>(mcnt, log_nom, ties, sum_hz, chunk_off, acc);
        finalize_kernel<<<1, 1, 0, stream>>>(acc, out);
    }
}

// Round 6
// 621.181 us; speedup vs baseline: 1.0089x; 1.0089x over previous
//
#include <hip/hip_runtime.h>

#define TMAXV 100000
#define CHUNK 256
#define NCHUNK ((TMAXV + CHUNK - 1) / CHUNK)   // 391
#define NTPAD (NCHUNK * CHUNK)                  // 100096 padded slots
#define NXCD 8
#define TILE 4096
#define RPT 16                                  // records per thread per tile
#define HSCALE 4096.0f                          // fixed-point scale for h
#define HINV (1.0f / 4096.0f)
#define THSHIFT 42                              // cm lives in bits [63:42] of packed

// Strategy (round 6): per-XCD replicated histograms + WORKGROUP-scope atomics.
// Agent-scope atomics on gfx950 bypass the per-XCD L2 (sc1 -> memory-side RMW,
// ~21 B HBM write per atomic -- measured 402 MB WRITE_SIZE in round 5).
// Workgroup-scope atomics stay cached in the local L2. Each replica is touched
// only by blocks on its own XCD (selected via HW_REG_XCC_ID), so L2-local RMW
// is correct XCD-wide; inter-dispatch L2 writeback (CP) makes the merge kernel
// see the final values (same mechanism that made rounds 3-4 val[] flow work).
//   sh[t]   += round(exp(x)*4096)                (u32, all records)
//   cmth[t] += (1<<42) | round(exp(x)*4096)      (u64, events: cm|th packed)
// Bounds: per-t ties ~84 (max ~140): th <= 545M < 2^42, cm < 2^22, sh < 2^32.

__device__ __forceinline__ int xcc_id() {
    unsigned x;
    asm volatile("s_getreg_b32 %0, hwreg(HW_REG_XCC_ID)" : "=s"(x));
    return (int)(x & (NXCD - 1));
}

__device__ __forceinline__ void atom_wg_u32(unsigned* p, unsigned v) {
    __hip_atomic_fetch_add(p, v, __ATOMIC_RELAXED, __HIP_MEMORY_SCOPE_WORKGROUP);
}
__device__ __forceinline__ void atom_wg_u64(unsigned long long* p, unsigned long long v) {
    __hip_atomic_fetch_add(p, v, __ATOMIC_RELAXED, __HIP_MEMORY_SCOPE_WORKGROUP);
}

// ---------------- block reduce helpers (blockDim.x == 256) ----------------
__device__ __forceinline__ float block_reduce_sum(float v, float* sdata) {
    int lane = threadIdx.x & 63;
    int wid  = threadIdx.x >> 6;
    #pragma unroll
    for (int off = 32; off > 0; off >>= 1)
        v += __shfl_down(v, off, 64);
    if (lane == 0) sdata[wid] = v;
    __syncthreads();
    if (wid == 0) {
        v = (lane < 4) ? sdata[lane] : 0.0f;
        v += __shfl_down(v, 2, 64);
        v += __shfl_down(v, 1, 64);
    }
    return v;  // valid in thread 0
}

__device__ __forceinline__ double block_reduce_sum_d(double v, double* sdata) {
    int lane = threadIdx.x & 63;
    int wid  = threadIdx.x >> 6;
    #pragma unroll
    for (int off = 32; off > 0; off >>= 1)
        v += __shfl_down(v, off, 64);
    if (lane == 0) sdata[wid] = v;
    __syncthreads();
    if (wid == 0) {
        v = (lane < 4) ? sdata[lane] : 0.0;
        v += __shfl_down(v, 2, 64);
        v += __shfl_down(v, 1, 64);
    }
    return v;  // valid in thread 0
}

// ================= FAST PATH =============================================

// ---- P1: one-pass histogram into the local XCD's replica (L2-cached RMW) ----
__global__ __launch_bounds__(256, 8)
void hist_direct_kernel(const float* __restrict__ lh,
                        const int*   __restrict__ tgt,
                        const int*   __restrict__ ev,
                        unsigned* __restrict__ sh_all,
                        unsigned long long* __restrict__ cmth_all,
                        double* __restrict__ acc, int n) {
    __shared__ float sdata[4];
    int tid = threadIdx.x;
    int xcd = xcc_id();
    unsigned*           shr = sh_all   + (size_t)xcd * NTPAD;
    unsigned long long* cmr = cmth_all + (size_t)xcd * NTPAD;
    float xl = 0.f;

#define PROC_REC(tt, ee, xx)                                                   \
    {                                                                          \
        unsigned hf = __float2uint_rn(__expf(xx) * HSCALE);                    \
        if (hf > 0x3FFFFFu) hf = 0x3FFFFFu;                                    \
        atom_wg_u32(shr + (tt), hf);                                           \
        if ((ee) & 1) {                                                        \
            atom_wg_u64(cmr + (tt), (1ull << THSHIFT) | (unsigned long long)hf); \
            xl += (xx);                                                        \
        }                                                                      \
    }

    for (long long lo = (long long)blockIdx.x * TILE; lo < n;
         lo += (long long)gridDim.x * TILE) {
        if (lo + TILE <= n) {
            const int4*   tgt4 = (const int4*)(tgt + lo);
            const int4*   ev4  = (const int4*)(ev + lo);
            const float4* lh4  = (const float4*)(lh + lo);
            #pragma unroll
            for (int q = 0; q < RPT / 4; ++q) {
                int idx = q * 256 + tid;
                int4   t4 = tgt4[idx];
                int4   e4 = ev4[idx];
                float4 x4 = lh4[idx];
                PROC_REC(t4.x, e4.x, x4.x);
                PROC_REC(t4.y, e4.y, x4.y);
                PROC_REC(t4.z, e4.z, x4.z);
                PROC_REC(t4.w, e4.w, x4.w);
            }
        } else {
            for (long long i = lo + tid; i < n; i += 256) {
                int t = tgt[i]; int e = ev[i]; float x = lh[i];
                PROC_REC(t, e, x);
            }
        }
    }
#undef PROC_REC

    float rl = block_reduce_sum(xl, sdata);
    if (tid == 0) unsafeAtomicAdd(&acc[2], (double)rl);   // native f64 atomic
}

// ---- P2: merge 8 replicas + per-chunk totals ----
__global__ void merge_chunk_kernel(const unsigned* __restrict__ sh_all,
                                   const unsigned long long* __restrict__ cmth_all,
                                   float* __restrict__ sh_f,
                                   unsigned long long* __restrict__ cmth_m,
                                   float* __restrict__ chunk_sum) {
    __shared__ float sdata[4];
    int t = blockIdx.x * CHUNK + threadIdx.x;
    unsigned s = 0u;
    unsigned long long p = 0ull;
    #pragma unroll
    for (int x = 0; x < NXCD; ++x) {
        s += sh_all[(size_t)x * NTPAD + t];
        p += cmth_all[(size_t)x * NTPAD + t];
    }
    float sv = (float)s * HINV;
    sh_f[t]   = sv;
    cmth_m[t] = p;
    float v = block_reduce_sum(sv, sdata);
    if (threadIdx.x == 0) chunk_sum[blockIdx.x] = v;
}

// ---- P3: per-chunk suffix + Efron; last-done block finalizes the output ----
__global__ void pll_suffix_kernel(const float* __restrict__ sh_f,
                                  const unsigned long long* __restrict__ cmth_m,
                                  const float* __restrict__ chunk_sum,
                                  double* __restrict__ acc,
                                  unsigned* __restrict__ done,
                                  float* __restrict__ out) {
    __shared__ float sf[CHUNK];
    __shared__ float sdata[4];
    __shared__ float sdata2[4];
    __shared__ double dsd[4];
    __shared__ double doff;
    int tid = threadIdx.x;
    int b   = blockIdx.x;
    int t   = b * CHUNK + tid;
    float sh = sh_f[t];
    unsigned long long pk = cmth_m[t];
    unsigned cmu = (unsigned)(pk >> THSHIFT);
    float th = (float)(pk & ((1ull << THSHIFT) - 1)) * HINV;
    sf[tid] = sh;
    __syncthreads();
    for (int off = 1; off < CHUNK; off <<= 1) {
        float add = (tid + off < CHUNK) ? sf[tid + off] : 0.0f;
        __syncthreads();
        sf[tid] += add;
        __syncthreads();
    }
    // strict-suffix over later chunks (double)
    double mysum = 0.0;
    for (int j = b + 1 + tid; j < NCHUNK; j += 256)
        mysum += (double)chunk_sum[j];
    double red = block_reduce_sum_d(mysum, dsd);
    if (tid == 0) doff = red;
    __syncthreads();
    double off_d = doff;

    float pll = 0.0f, inc = 0.0f;
    if (t < TMAXV && cmu > 0u) {
        float cm   = (float)cmu;
        float D    = (float)(off_d + (double)sf[tid]);
        int   mi   = (int)cmu;
        float step = th / cm;
        float s = 0.0f;
        for (int l = 0; l < mi; ++l)
            s += __logf(D - (float)l * step);
        pll = -s;            // log_nom handled globally via acc[2]
        inc = 1.0f;
    }
    float rp = block_reduce_sum(pll, sdata);
    __syncthreads();
    float ri = block_reduce_sum(inc, sdata2);
    if (tid == 0) {
        unsafeAtomicAdd(&acc[0], (double)rp);
        unsafeAtomicAdd(&acc[1], (double)ri);
        __threadfence();
        unsigned prev = __hip_atomic_fetch_add(done, 1u, __ATOMIC_ACQ_REL, __HIP_MEMORY_SCOPE_AGENT);
        if (prev == (unsigned)(gridDim.x - 1)) {
            double a0 = __hip_atomic_load(&acc[0], __ATOMIC_ACQUIRE, __HIP_MEMORY_SCOPE_AGENT);
            double a1 = __hip_atomic_load(&acc[1], __ATOMIC_RELAXED, __HIP_MEMORY_SCOPE_AGENT);
            double a2 = __hip_atomic_load(&acc[2], __ATOMIC_RELAXED, __HIP_MEMORY_SCOPE_AGENT);
            out[0] = (a1 > 0.0) ? (float)(-(a0 + a2) / a1) : 0.0f;
        }
    }
}

// ---- finalize (fallback path only) ----
__global__ void finalize_kernel(const double* __restrict__ acc,
                                float* __restrict__ out) {
    double cnt = acc[1];
    out[0] = (cnt > 0.0) ? (float)(-(acc[0] + acc[2]) / cnt) : 0.0f;
}

// ================= FALLBACK: round-1 global-atomic histogram ==============
__global__ void hist_kernel(const float* __restrict__ lh,
                            const int*   __restrict__ tgt,
                            const int*   __restrict__ ev,
                            float* __restrict__ sum_hz,
                            float* __restrict__ mcnt,
                            float* __restrict__ log_nom,
                            float* __restrict__ ties,
                            int n) {
    int i = blockIdx.x * blockDim.x + threadIdx.x;
    if (i >= n) return;
    float x = lh[i];
    int   t = tgt[i];
    int   e = ev[i];
    float h = __expf(x);
    unsafeAtomicAdd(&sum_hz[t], h);
    if (e) {
        unsafeAtomicAdd(&mcnt[t], 1.0f);
        unsafeAtomicAdd(&log_nom[t], x);
        unsafeAtomicAdd(&ties[t], h);
    }
}

__global__ void chunk_sum_kernel(const float* __restrict__ sum_hz,
                                 float* __restrict__ chunk_sum) {
    __shared__ float sdata[4];
    int i = blockIdx.x * CHUNK + threadIdx.x;
    float v = (i < TMAXV) ? sum_hz[i] : 0.0f;
    v = block_reduce_sum(v, sdata);
    if (threadIdx.x == 0) chunk_sum[blockIdx.x] = v;
}

__global__ void chunk_scan_kernel(const float* __restrict__ chunk_sum,
                                  double* __restrict__ chunk_off) {
    __shared__ double ds[512];
    int tid = threadIdx.x;
    double own = (tid < NCHUNK) ? (double)chunk_sum[tid] : 0.0;
    ds[tid] = own;
    __syncthreads();
    for (int off = 1; off < 512; off <<= 1) {
        double add = (tid + off < 512) ? ds[tid + off] : 0.0;
        __syncthreads();
        ds[tid] += add;
        __syncthreads();
    }
    if (tid < NCHUNK) chunk_off[tid] = ds[tid] - own;
}

__global__ void pll_kernel(const float* __restrict__ mcnt,
                           const float* __restrict__ log_nom,
                           const float* __restrict__ ties,
                           const float* __restrict__ sum_hz,
                           const double* __restrict__ chunk_off,
                           double* __restrict__ acc) {
    __shared__ float sf[CHUNK];
    __shared__ float sdata[4];
    __shared__ float sdata2[4];
    int tid = threadIdx.x;
    int t   = blockIdx.x * CHUNK + tid;
    float v = (t < TMAXV) ? sum_hz[t] : 0.0f;
    sf[tid] = v;
    __syncthreads();
    for (int off = 1; off < CHUNK; off <<= 1) {
        float add = (tid + off < CHUNK) ? sf[tid + off] : 0.0f;
        __syncthreads();
        sf[tid] += add;
        __syncthreads();
    }
    float pll = 0.0f, inc = 0.0f;
    if (t < TMAXV) {
        float mv = mcnt[t];
        if (mv > 0.5f) {
            float D    = (float)(chunk_off[blockIdx.x] + (double)sf[tid]);
            float T    = ties[t];
            int   mi   = (int)(mv + 0.5f);
            float step = T / mv;
            float s = 0.0f;
            for (int l = 0; l < mi; ++l)
                s += __logf(D - (float)l * step);
            pll = log_nom[t] - s;
            inc = 1.0f;
        }
    }
    float rp = block_reduce_sum(pll, sdata);
    __syncthreads();
    float ri = block_reduce_sum(inc, sdata2);
    if (threadIdx.x == 0) {
        atomicAdd(&acc[0], (double)rp);
        atomicAdd(&acc[1], (double)ri);
    }
}

// =========================================================================
extern "C" void kernel_launch(void* const* d_in, const int* in_sizes, int n_in,
                              void* d_out, int out_size, void* d_ws, size_t ws_size,
                              hipStream_t stream) {
    const float* lh  = (const float*)d_in[0];
    const int*   tgt = (const int*)d_in[1];
    const int*   ev  = (const int*)d_in[2];
    float*       out = (float*)d_out;
    int n  = in_sizes[0];
    int nt = (n + TILE - 1) / TILE;   // number of tiles

    char* ws = (char*)d_ws;
    size_t off = 0;
    auto take = [&](size_t bytes, size_t align) {
        off = (off + align - 1) & ~(align - 1);
        size_t r = off; off += bytes; return r;
    };
    // ---- zero region (single memset, ~9.6 MB) ----
    size_t o_acc   = take(32, 16);                           // 3 doubles used
    size_t o_done  = take(16, 16);                           // pll done counter
    size_t o_csum  = take((size_t)NCHUNK * 4, 16);           // chunk_sum (float)
    size_t o_shall = take((size_t)NXCD * NTPAD * 4, 256);    // per-XCD sh replicas
    size_t o_cmall = take((size_t)NXCD * NTPAD * 8, 256);    // per-XCD cm|th replicas
    size_t zero_end = off;
    // ---- non-zeroed (fully written by merge) ----
    size_t o_shf   = take((size_t)NTPAD * 4, 16);            // merged sh (float)
    size_t o_cmm   = take((size_t)NTPAD * 8, 16);            // merged cm|th (u64)
    size_t need    = off;                                    // ~10.9 MB

    if (ws_size >= need) {
        // ================= fast path =================
        double*             acc       = (double*)(ws + o_acc);
        unsigned*           done      = (unsigned*)(ws + o_done);
        float*              chunk_sum = (float*)(ws + o_csum);
        unsigned*           sh_all    = (unsigned*)(ws + o_shall);
        unsigned long long* cmth_all  = (unsigned long long*)(ws + o_cmall);
        float*              sh_f      = (float*)(ws + o_shf);
        unsigned long long* cmth_m    = (unsigned long long*)(ws + o_cmm);

        hipMemsetAsync(ws, 0, zero_end, stream);   // ~9.6 MB

        int grid = nt < 2048 ? nt : 2048;
        hist_direct_kernel<<<grid, 256, 0, stream>>>(lh, tgt, ev, sh_all, cmth_all,
                                                     acc, n);
        merge_chunk_kernel<<<NCHUNK, 256, 0, stream>>>(sh_all, cmth_all,
                                                       sh_f, cmth_m, chunk_sum);
        pll_suffix_kernel<<<NCHUNK, 256, 0, stream>>>(sh_f, cmth_m, chunk_sum,
                                                      acc, done, out);
    } else {
        // ================= fallback (round-1 style) =================
        size_t f = 0;
        auto ftake = [&](size_t bytes, size_t align) {
            f = (f + align - 1) & ~(align - 1);
            size_t r = f; f += bytes; return r;
        };
        size_t f_acc  = ftake(32, 16);
        size_t f_sum  = ftake((size_t)TMAXV * 4, 16);
        size_t f_m    = ftake((size_t)TMAXV * 4, 16);
        size_t f_ln   = ftake((size_t)TMAXV * 4, 16);
        size_t f_ties = ftake((size_t)TMAXV * 4, 16);
        size_t zb     = f;
        size_t f_csum = ftake((size_t)NCHUNK * 4, 16);
        size_t f_coff = ftake((size_t)NCHUNK * 8, 8);

        double* acc     = (double*)(ws + f_acc);
        float*  sum_hz  = (float*)(ws + f_sum);
        float*  mcnt    = (float*)(ws + f_m);
        float*  log_nom = (float*)(ws + f_ln);
        float*  ties    = (float*)(ws + f_ties);
        float*  chunk_sum = (float*)(ws + f_csum);
        double* chunk_off = (double*)(ws + f_coff);

        hipMemsetAsync(d_ws, 0, zb, stream);

        hist_kernel<<<(n + 255) / 256, 256, 0, stream>>>(lh, tgt, ev, sum_hz, mcnt, log_nom, ties, n);
        chunk_sum_kernel<<<NCHUNK, 256, 0, stream>>>(sum_hz, chunk_sum);
        chunk_scan_kernel<<<1, 512, 0, stream>>>(chunk_sum, chunk_off);
        pll_kernel<<<NCHUNK, 256, 0, stream>>>(mcnt, log_nom, ties, sum_hz, chunk_off, acc);
        finalize_kernel<<<1, 1, 0, stream>>>(acc, out);
    }
}

// Round 7
// 263.247 us; speedup vs baseline: 2.3806x; 2.3597x over previous
//
#include <hip/hip_runtime.h>

#define TMAXV 100000
#define CHUNK 256
#define NCHUNK ((TMAXV + CHUNK - 1) / CHUNK)   // 391
#define WB 512                                  // bucket width in t
#define LOGWB 9
#define SB ((TMAXV + WB - 1) / WB)              // 196 buckets
#define SBP 256                                 // padded bucket count (scan width)
#define TILE 2048                               // small tile -> 13 KB LDS -> 8 blk/CU
#define RPT 8                                   // records per thread (TILE/256)
#define KS 16                                   // slices per bucket in hist phase
#define NREP 2                                  // LDS histogram replicas
#define HSCALE 4096.0f                          // fixed-point scale for h
#define HINV (1.0f / 4096.0f)

// record encoding (32 bits): [31]=event  [30:9]=round(exp(x)*4096) (22-bit fixed
// point, clamped)  [8:0]=slot (t & 511). Abs quantization error <= 2^-13.
// Per-slot sums are EXACT integer adds; only integer LDS/global atomics are
// native-fast on this toolchain (rounds 1-3); global atomic RMW streams are
// memory-side and rate-bound (rounds 5-6) -> bucket-sort + LDS hist pipeline.

// ---------------- block reduce helpers (blockDim.x == 256) ----------------
__device__ __forceinline__ float block_reduce_sum(float v, float* sdata) {
    int lane = threadIdx.x & 63;
    int wid  = threadIdx.x >> 6;
    #pragma unroll
    for (int off = 32; off > 0; off >>= 1)
        v += __shfl_down(v, off, 64);
    if (lane == 0) sdata[wid] = v;
    __syncthreads();
    if (wid == 0) {
        v = (lane < 4) ? sdata[lane] : 0.0f;
        v += __shfl_down(v, 2, 64);
        v += __shfl_down(v, 1, 64);
    }
    return v;  // valid in thread 0
}

__device__ __forceinline__ double block_reduce_sum_d(double v, double* sdata) {
    int lane = threadIdx.x & 63;
    int wid  = threadIdx.x >> 6;
    #pragma unroll
    for (int off = 32; off > 0; off >>= 1)
        v += __shfl_down(v, off, 64);
    if (lane == 0) sdata[wid] = v;
    __syncthreads();
    if (wid == 0) {
        v = (lane < 4) ? sdata[lane] : 0.0;
        v += __shfl_down(v, 2, 64);
        v += __shfl_down(v, 1, 64);
    }
    return v;  // valid in thread 0
}

__device__ __forceinline__ unsigned encode_rec(float x, int t, int e) {
    float h = __expf(x);
    unsigned hf = (unsigned)__float2uint_rn(h * HSCALE);
    if (hf > 0x3FFFFFu) hf = 0x3FFFFFu;
    return (hf << 9)
         | (unsigned)(t & (WB - 1))
         | ((unsigned)e << 31);
}

// ================= FAST PATH =============================================

// ---- P1: per-tile counts + in-tile exclusive scan, tile-major (coalesced)
//      also zeroes the accumulator region (replaces hipMemsetAsync dispatch)
__global__ void count_pfx_kernel(const int* __restrict__ tgt,
                                 int* __restrict__ pfx_arr,
                                 int* __restrict__ cnt_t,
                                 unsigned* __restrict__ zero_base,
                                 int nzero_dw, int n) {
    __shared__ int lc[SBP];
    __shared__ int ls[SBP];
    int tid = threadIdx.x, tile = blockIdx.x;
    // zero done/chunk_sum/triple arrays (used only by later kernels)
    for (int i = tile * 256 + tid; i < nzero_dw; i += gridDim.x * 256)
        zero_base[i] = 0u;
    lc[tid] = 0;
    __syncthreads();
    int lo = tile * TILE;
    if (lo + TILE <= n) {
        const int4* tgt4 = (const int4*)(tgt + lo);
        #pragma unroll
        for (int q = 0; q < RPT / 4; ++q) {
            int4 t4 = tgt4[q * 256 + tid];
            atomicAdd(&lc[t4.x >> LOGWB], 1);
            atomicAdd(&lc[t4.y >> LOGWB], 1);
            atomicAdd(&lc[t4.z >> LOGWB], 1);
            atomicAdd(&lc[t4.w >> LOGWB], 1);
        }
    } else {
        int hi = min(n, lo + TILE);
        for (int i = lo + tid; i < hi; i += 256)
            atomicAdd(&lc[tgt[i] >> LOGWB], 1);
    }
    __syncthreads();
    int c0 = lc[tid];
    ls[tid] = c0;
    __syncthreads();
    for (int off = 1; off < SBP; off <<= 1) {
        int a = (tid >= off) ? ls[tid - off] : 0;
        __syncthreads();
        ls[tid] += a;
        __syncthreads();
    }
    size_t rb = (size_t)tile * SBP;
    pfx_arr[rb + tid] = ls[tid] - c0;
    cnt_t[rb + tid] = c0;
}

// ---- P2: per-bucket scan over tiles. 8 tiles/thread serial prefix + ONE
//      block scan per 2048 tiles. Last-done block performs the bucket-base
//      exclusive scan. Grid = SBP blocks.
__global__ void tile_scan_kernel(const int* __restrict__ cnt_t,
                                 int* __restrict__ tilebase_t,
                                 int* __restrict__ totals,
                                 int* __restrict__ base,
                                 unsigned* __restrict__ done,
                                 int nt, int n) {
    __shared__ int ls[256];
    __shared__ int lastFlag;
    int s = blockIdx.x, tid = threadIdx.x;
    int run = 0;
    for (int t0 = 0; t0 < nt; t0 += 256 * 8) {
        int c[8];
        #pragma unroll
        for (int u = 0; u < 8; ++u) {
            int t = t0 + tid * 8 + u;
            c[u] = (t < nt) ? cnt_t[(size_t)t * SBP + s] : 0;
        }
        // exclusive prefix within thread
        int tot = 0;
        #pragma unroll
        for (int u = 0; u < 8; ++u) { int v = c[u]; c[u] = tot; tot += v; }
        // block scan of per-thread totals
        ls[tid] = tot;
        __syncthreads();
        for (int off = 1; off < 256; off <<= 1) {
            int a = (tid >= off) ? ls[tid - off] : 0;
            __syncthreads();
            ls[tid] += a;
            __syncthreads();
        }
        int excl = ls[tid] - tot;
        int btot = ls[255];
        #pragma unroll
        for (int u = 0; u < 8; ++u) {
            int t = t0 + tid * 8 + u;
            if (t < nt) tilebase_t[(size_t)t * SBP + s] = run + excl + c[u];
        }
        run += btot;
        __syncthreads();
    }
    if (tid == 0) {
        __hip_atomic_store(&totals[s], run, __ATOMIC_RELEASE, __HIP_MEMORY_SCOPE_AGENT);
        unsigned prev = __hip_atomic_fetch_add(done, 1u, __ATOMIC_ACQ_REL, __HIP_MEMORY_SCOPE_AGENT);
        lastFlag = (prev == (unsigned)(gridDim.x - 1)) ? 1 : 0;
    }
    __syncthreads();
    if (lastFlag) {
        int c = __hip_atomic_load(&totals[tid], __ATOMIC_ACQUIRE, __HIP_MEMORY_SCOPE_AGENT);
        ls[tid] = c;
        __syncthreads();
        for (int off = 1; off < 256; off <<= 1) {
            int a = (tid >= off) ? ls[tid - off] : 0;
            __syncthreads();
            ls[tid] += a;
            __syncthreads();
        }
        base[tid] = ls[tid] - c;
        if (tid == 0) base[SBP] = n;
    }
}

// ---- P3: streamed scatter — 13 KB LDS -> 8 blocks/CU (wave-capped),
//      halved per-bucket LDS-atomic chains, coalesced tilebase read
__global__ void scatter_kernel(const float* __restrict__ lh,
                               const int*   __restrict__ tgt,
                               const int*   __restrict__ ev,
                               const int*   __restrict__ pfx_arr,
                               const int*   __restrict__ tilebase_t,
                               const int*   __restrict__ base,
                               unsigned* __restrict__ val,
                               double* __restrict__ acc, int n, int nt) {
    __shared__ unsigned fu[TILE];           // 8 KB
    __shared__ unsigned char bidv[TILE];    // 2 KB
    __shared__ int pfx[SBP];                // 1 KB
    __shared__ int tb[SBP];                 // 1 KB
    __shared__ int lrank[SBP];              // 1 KB
    __shared__ float sdata[4];
    int tid  = threadIdx.x;
    int tile = blockIdx.x;
    int lo   = tile * TILE;
    int cnt_here = min(TILE, n - lo);
    size_t rb = (size_t)tile * SBP;

    pfx[tid]   = pfx_arr[rb + tid];
    tb[tid]    = base[tid] + tilebase_t[rb + tid];
    lrank[tid] = 0;
    __syncthreads();

    float xl = 0.f;
    if (lo + TILE <= n) {
        const int4*   tgt4 = (const int4*)(tgt + lo);
        const int4*   ev4  = (const int4*)(ev + lo);
        const float4* lh4  = (const float4*)(lh + lo);
        #pragma unroll
        for (int q = 0; q < RPT / 4; ++q) {
            int idx = q * 256 + tid;
            int4   t4 = tgt4[idx];
            int4   e4 = ev4[idx];
            float4 x4 = lh4[idx];
            {
                int b = t4.x >> LOGWB; unsigned r = encode_rec(x4.x, t4.x, e4.x & 1);
                int k = atomicAdd(&lrank[b], 1); int pos = pfx[b] + k;
                fu[pos] = r; bidv[pos] = (unsigned char)b; if (e4.x & 1) xl += x4.x;
            }
            {
                int b = t4.y >> LOGWB; unsigned r = encode_rec(x4.y, t4.y, e4.y & 1);
                int k = atomicAdd(&lrank[b], 1); int pos = pfx[b] + k;
                fu[pos] = r; bidv[pos] = (unsigned char)b; if (e4.y & 1) xl += x4.y;
            }
            {
                int b = t4.z >> LOGWB; unsigned r = encode_rec(x4.z, t4.z, e4.z & 1);
                int k = atomicAdd(&lrank[b], 1); int pos = pfx[b] + k;
                fu[pos] = r; bidv[pos] = (unsigned char)b; if (e4.z & 1) xl += x4.z;
            }
            {
                int b = t4.w >> LOGWB; unsigned r = encode_rec(x4.w, t4.w, e4.w & 1);
                int k = atomicAdd(&lrank[b], 1); int pos = pfx[b] + k;
                fu[pos] = r; bidv[pos] = (unsigned char)b; if (e4.w & 1) xl += x4.w;
            }
        }
    } else {
        for (int i = lo + tid; i < lo + cnt_here; i += 256) {
            int t = tgt[i]; int e = ev[i] & 1; float x = lh[i];
            int b = t >> LOGWB; unsigned r = encode_rec(x, t, e);
            int rr = atomicAdd(&lrank[b], 1); int pos = pfx[b] + rr;
            fu[pos] = r; bidv[pos] = (unsigned char)b; if (e) xl += x;
        }
    }
    __syncthreads();

    // write-out: paired LDS reads, run-coalesced stores (~10-rec runs)
    int pairs = cnt_here >> 1;
    const uint2* fu2 = (const uint2*)fu;
    for (int q = tid; q < pairs; q += 256) {
        uint2 bb = fu2[q];
        int p0 = q * 2;
        int b0 = (int)bidv[p0];
        int b1 = (int)bidv[p0 + 1];
        val[tb[b0] + (p0     - pfx[b0])] = bb.x;
        val[tb[b1] + (p0 + 1 - pfx[b1])] = bb.y;
    }
    if ((cnt_here & 1) && tid == 0) {
        int p = cnt_here - 1;
        int b = (int)bidv[p];
        val[tb[b] + (p - pfx[b])] = fu[p];
    }

    float rl = block_reduce_sum(xl, sdata);
    if (tid == 0) unsafeAtomicAdd(&acc[2], (double)rl);   // native f64 atomic
}

// ---- P4: direct LDS histogram, INTEGER atomics only (ds_add_u32 native).
//      Fixed-point h from the record; 2 replicas (wave parity). Grid = SB*KS.
__global__ void bucket_hist_kernel(const unsigned* __restrict__ val,
                                   const int* __restrict__ base,
                                   unsigned* __restrict__ sh_g,
                                   unsigned* __restrict__ cm_g,
                                   unsigned* __restrict__ th_g,
                                   float* __restrict__ chunk_sum) {
    __shared__ unsigned shi[NREP][WB];   // 4 KB
    __shared__ unsigned cmi[NREP][WB];   // 4 KB
    __shared__ unsigned thi[NREP][WB];   // 4 KB
    __shared__ float sdata[4];
    __shared__ float sdata2[4];
    int tid = threadIdx.x;
    int rep = (tid >> 6) & (NREP - 1);   // wave parity picks replica
    int b   = blockIdx.x >> 4;           // KS == 16
    int k   = blockIdx.x & (KS - 1);
    int lo0 = base[b], len = base[b + 1] - lo0;
    int lo  = lo0 + (int)(((long long)len * k) / KS);
    int hi  = lo0 + (int)(((long long)len * (k + 1)) / KS);

    #pragma unroll
    for (int u = 0; u < NREP * WB / 256; ++u) {
        ((unsigned*)shi)[u * 256 + tid] = 0u;
        ((unsigned*)cmi)[u * 256 + tid] = 0u;
        ((unsigned*)thi)[u * 256 + tid] = 0u;
    }
    __syncthreads();

    for (int i = lo + tid; i < hi; i += 256) {
        unsigned bits = val[i];
        int      s  = (int)(bits & (WB - 1));
        unsigned hf = (bits >> 9) & 0x3FFFFFu;
        atomicAdd(&shi[rep][s], hf);             // native ds_add_u32
        if (bits >> 31) {
            atomicAdd(&cmi[rep][s], 1u);
            atomicAdd(&thi[rep][s], hf);
        }
    }
    __syncthreads();

    // merge replicas, push per-t triples to global (native u32 atomics),
    // and per-chunk float totals (bucket spans chunks 2b and 2b+1)
    unsigned s0 = shi[0][tid]       + shi[1][tid];
    unsigned s1 = shi[0][tid + 256] + shi[1][tid + 256];
    unsigned c0 = cmi[0][tid]       + cmi[1][tid];
    unsigned c1 = cmi[0][tid + 256] + cmi[1][tid + 256];
    unsigned t0v = thi[0][tid]       + thi[1][tid];
    unsigned t1v = thi[0][tid + 256] + thi[1][tid + 256];

    int t0 = b * WB + tid;
    if (s0)  atomicAdd(&sh_g[t0],       s0);
    if (s1)  atomicAdd(&sh_g[t0 + 256], s1);
    if (c0)  atomicAdd(&cm_g[t0],       c0);
    if (c1)  atomicAdd(&cm_g[t0 + 256], c1);
    if (t0v) atomicAdd(&th_g[t0],       t0v);
    if (t1v) atomicAdd(&th_g[t0 + 256], t1v);

    float r0 = block_reduce_sum((float)s0 * HINV, sdata);
    __syncthreads();
    float r1 = block_reduce_sum((float)s1 * HINV, sdata2);
    if (tid == 0) {
        unsafeAtomicAdd(&chunk_sum[2 * b],     r0);   // native global f32 atomic
        unsafeAtomicAdd(&chunk_sum[2 * b + 1], r1);
    }
}

// ---- P5: per-chunk suffix + Efron; last-done block finalizes the output
__global__ void pll_suffix_kernel(const unsigned* __restrict__ sh_g,
                                  const unsigned* __restrict__ cm_g,
                                  const unsigned* __restrict__ th_g,
                                  const float* __restrict__ chunk_sum,
                                  double* __restrict__ acc,
                                  unsigned* __restrict__ done,
                                  float* __restrict__ out) {
    __shared__ float sf[CHUNK];
    __shared__ float sdata[4];
    __shared__ float sdata2[4];
    __shared__ double dsd[4];
    __shared__ double doff;
    int tid = threadIdx.x;
    int b   = blockIdx.x;
    int t   = b * CHUNK + tid;
    float sh = (float)sh_g[t] * HINV;
    unsigned cmu = cm_g[t];
    float th = (float)th_g[t] * HINV;
    sf[tid] = sh;
    __syncthreads();
    for (int off = 1; off < CHUNK; off <<= 1) {
        float add = (tid + off < CHUNK) ? sf[tid + off] : 0.0f;
        __syncthreads();
        sf[tid] += add;
        __syncthreads();
    }
    // strict-suffix over later chunks (double)
    double mysum = 0.0;
    for (int j = b + 1 + tid; j < NCHUNK; j += 256)
        mysum += (double)chunk_sum[j];
    double red = block_reduce_sum_d(mysum, dsd);
    if (tid == 0) doff = red;
    __syncthreads();
    double off_d = doff;

    float pll = 0.0f, inc = 0.0f;
    if (t < TMAXV && cmu > 0u) {
        float cm   = (float)cmu;
        float D    = (float)(off_d + (double)sf[tid]);
        int   mi   = (int)cmu;
        float step = th / cm;
        float s = 0.0f;
        for (int l = 0; l < mi; ++l)
            s += __logf(D - (float)l * step);
        pll = -s;            // log_nom handled globally via acc[2]
        inc = 1.0f;
    }
    float rp = block_reduce_sum(pll, sdata);
    __syncthreads();
    float ri = block_reduce_sum(inc, sdata2);
    if (tid == 0) {
        unsafeAtomicAdd(&acc[0], (double)rp);
        unsafeAtomicAdd(&acc[1], (double)ri);
        __threadfence();
        unsigned prev = __hip_atomic_fetch_add(done, 1u, __ATOMIC_ACQ_REL, __HIP_MEMORY_SCOPE_AGENT);
        if (prev == (unsigned)(gridDim.x - 1)) {
            double a0 = __hip_atomic_load(&acc[0], __ATOMIC_ACQUIRE, __HIP_MEMORY_SCOPE_AGENT);
            double a1 = __hip_atomic_load(&acc[1], __ATOMIC_RELAXED, __HIP_MEMORY_SCOPE_AGENT);
            double a2 = __hip_atomic_load(&acc[2], __ATOMIC_RELAXED, __HIP_MEMORY_SCOPE_AGENT);
            out[0] = (a1 > 0.0) ? (float)(-(a0 + a2) / a1) : 0.0f;
        }
    }
}

// ---- finalize (fallback path only) ----
__global__ void finalize_kernel(const double* __restrict__ acc,
                                float* __restrict__ out) {
    double cnt = acc[1];
    out[0] = (cnt > 0.0) ? (float)(-(acc[0] + acc[2]) / cnt) : 0.0f;
}

// ================= FALLBACK: round-1 global-atomic histogram ==============
__global__ void hist_kernel(const float* __restrict__ lh,
                            const int*   __restrict__ tgt,
                            const int*   __restrict__ ev,
                            float* __restrict__ sum_hz,
                            float* __restrict__ mcnt,
                            float* __restrict__ log_nom,
                            float* __restrict__ ties,
                            int n) {
    int i = blockIdx.x * blockDim.x + threadIdx.x;
    if (i >= n) return;
    float x = lh[i];
    int   t = tgt[i];
    int   e = ev[i];
    float h = __expf(x);
    unsafeAtomicAdd(&sum_hz[t], h);
    if (e) {
        unsafeAtomicAdd(&mcnt[t], 1.0f);
        unsafeAtomicAdd(&log_nom[t], x);
        unsafeAtomicAdd(&ties[t], h);
    }
}

__global__ void chunk_sum_kernel(const float* __restrict__ sum_hz,
                                 float* __restrict__ chunk_sum) {
    __shared__ float sdata[4];
    int i = blockIdx.x * CHUNK + threadIdx.x;
    float v = (i < TMAXV) ? sum_hz[i] : 0.0f;
    v = block_reduce_sum(v, sdata);
    if (threadIdx.x == 0) chunk_sum[blockIdx.x] = v;
}

__global__ void chunk_scan_kernel(const float* __restrict__ chunk_sum,
                                  double* __restrict__ chunk_off) {
    __shared__ double ds[512];
    int tid = threadIdx.x;
    double own = (tid < NCHUNK) ? (double)chunk_sum[tid] : 0.0;
    ds[tid] = own;
    __syncthreads();
    for (int off = 1; off < 512; off <<= 1) {
        double add = (tid + off < 512) ? ds[tid + off] : 0.0;
        __syncthreads();
        ds[tid] += add;
        __syncthreads();
    }
    if (tid < NCHUNK) chunk_off[tid] = ds[tid] - own;
}

__global__ void pll_kernel(const float* __restrict__ mcnt,
                           const float* __restrict__ log_nom,
                           const float* __restrict__ ties,
                           const float* __restrict__ sum_hz,
                           const double* __restrict__ chunk_off,
                           double* __restrict__ acc) {
    __shared__ float sf[CHUNK];
    __shared__ float sdata[4];
    __shared__ float sdata2[4];
    int tid = threadIdx.x;
    int t   = blockIdx.x * CHUNK + tid;
    float v = (t < TMAXV) ? sum_hz[t] : 0.0f;
    sf[tid] = v;
    __syncthreads();
    for (int off = 1; off < CHUNK; off <<= 1) {
        float add = (tid + off < CHUNK) ? sf[tid + off] : 0.0f;
        __syncthreads();
        sf[tid] += add;
        __syncthreads();
    }
    float pll = 0.0f, inc = 0.0f;
    if (t < TMAXV) {
        float mv = mcnt[t];
        if (mv > 0.5f) {
            float D    = (float)(chunk_off[blockIdx.x] + (double)sf[tid]);
            float T    = ties[t];
            int   mi   = (int)(mv + 0.5f);
            float step = T / mv;
            float s = 0.0f;
            for (int l = 0; l < mi; ++l)
                s += __logf(D - (float)l * step);
            pll = log_nom[t] - s;
            inc = 1.0f;
        }
    }
    float rp = block_reduce_sum(pll, sdata);
    __syncthreads();
    float ri = block_reduce_sum(inc, sdata2);
    if (threadIdx.x == 0) {
        atomicAdd(&acc[0], (double)rp);
        atomicAdd(&acc[1], (double)ri);
    }
}

// =========================================================================
extern "C" void kernel_launch(void* const* d_in, const int* in_sizes, int n_in,
                              void* d_out, int out_size, void* d_ws, size_t ws_size,
                              hipStream_t stream) {
    const float* lh  = (const float*)d_in[0];
    const int*   tgt = (const int*)d_in[1];
    const int*   ev  = (const int*)d_in[2];
    float*       out = (float*)d_out;
    int n  = in_sizes[0];
    int nt = (n + TILE - 1) / TILE;   // number of tiles

    char* ws = (char*)d_ws;
    size_t off = 0;
    auto take = [&](size_t bytes, size_t align) {
        off = (off + align - 1) & ~(align - 1);
        size_t r = off; off += bytes; return r;
    };
    // ---- zero region (contiguous, zeroed by count_pfx grid-stride) ----
    size_t o_acc   = take(32, 16);                        // 3 doubles used
    size_t o_done  = take(16, 16);                        // done counters (scan, pll)
    size_t o_csum  = take((size_t)512 * 4, 16);           // chunk_sum (float)
    size_t o_shg   = take((size_t)SB * WB * 4, 16);       // per-t sum exp (u32 fx)
    size_t o_cmg   = take((size_t)SB * WB * 4, 16);       // per-t event count (u32)
    size_t o_thg   = take((size_t)SB * WB * 4, 16);       // per-t tie sum (u32 fx)
    size_t zero_bytes = off;                              // ~1.2 MB
    // ---- non-zeroed ----
    size_t o_base   = take((size_t)(SBP + 1) * 4, 16);
    size_t o_totals = take((size_t)SBP * 4, 16);
    size_t o_pfx    = take((size_t)nt * SBP * 4, 16);     // 4 MB
    size_t o_cntt   = take((size_t)nt * SBP * 4, 16);     // 4 MB
    size_t o_tbs    = take((size_t)nt * SBP * 4, 16);     // 4 MB
    size_t o_val    = take((size_t)n * 4, 16);            // 33.5 MB
    size_t need     = off;

    if (ws_size >= need) {
        // ================= fast path =================
        double*   acc       = (double*)(ws + o_acc);
        unsigned* done      = (unsigned*)(ws + o_done);
        float*    chunk_sum = (float*)(ws + o_csum);
        unsigned* sh_g      = (unsigned*)(ws + o_shg);
        unsigned* cm_g      = (unsigned*)(ws + o_cmg);
        unsigned* th_g      = (unsigned*)(ws + o_thg);
        int*      base      = (int*)(ws + o_base);
        int*      totals    = (int*)(ws + o_totals);
        int*      pfx_arr   = (int*)(ws + o_pfx);
        int*      cnt_t     = (int*)(ws + o_cntt);
        int*      tilebase_t= (int*)(ws + o_tbs);
        unsigned* val       = (unsigned*)(ws + o_val);

        count_pfx_kernel<<<nt, 256, 0, stream>>>(tgt, pfx_arr, cnt_t,
                                                 (unsigned*)ws, (int)(zero_bytes / 4), n);
        tile_scan_kernel<<<SBP, 256, 0, stream>>>(cnt_t, tilebase_t, totals, base,
                                                  done + 0, nt, n);
        scatter_kernel<<<nt, 256, 0, stream>>>(lh, tgt, ev, pfx_arr, tilebase_t, base,
                                               val, acc, n, nt);
        bucket_hist_kernel<<<SB * KS, 256, 0, stream>>>(val, base, sh_g, cm_g, th_g,
                                                        chunk_sum);
        pll_suffix_kernel<<<NCHUNK, 256, 0, stream>>>(sh_g, cm_g, th_g, chunk_sum,
                                                      acc, done + 1, out);
    } else {
        // ================= fallback (round-1 style) =================
        size_t f = 0;
        auto ftake = [&](size_t bytes, size_t align) {
            f = (f + align - 1) & ~(align - 1);
            size_t r = f; f += bytes; return r;
        };
        size_t f_acc  = ftake(32, 16);
        size_t f_sum  = ftake((size_t)TMAXV * 4, 16);
        size_t f_m    = ftake((size_t)TMAXV * 4, 16);
        size_t f_ln   = ftake((size_t)TMAXV * 4, 16);
        size_t f_ties = ftake((size_t)TMAXV * 4, 16);
        size_t zb     = f;
        size_t f_csum = ftake((size_t)NCHUNK * 4, 16);
        size_t f_coff = ftake((size_t)NCHUNK * 8, 8);

        double* acc     = (double*)(ws + f_acc);
        float*  sum_hz  = (float*)(ws + f_sum);
        float*  mcnt    = (float*)(ws + f_m);
        float*  log_nom = (float*)(ws + f_ln);
        float*  ties    = (float*)(ws + f_ties);
        float*  chunk_sum = (float*)(ws + f_csum);
        double* chunk_off = (double*)(ws + f_coff);

        hipMemsetAsync(d_ws, 0, zb, stream);

        hist_kernel<<<(n + 255) / 256, 256, 0, stream>>>(lh, tgt, ev, sum_hz, mcnt, log_nom, ties, n);
        chunk_sum_kernel<<<NCHUNK, 256, 0, stream>>>(sum_hz, chunk_sum);
        chunk_scan_kernel<<<1, 512, 0, stream>>>(chunk_sum, chunk_off);
        pll_kernel<<<NCHUNK, 256, 0, stream>>>(mcnt, log_nom, ties, sum_hz, chunk_off, acc);
        finalize_kernel<<<1, 1, 0, stream>>>(acc, out);
    }
}

// Round 8
// 218.556 us; speedup vs baseline: 2.8674x; 1.2045x over previous
//
#include <hip/hip_runtime.h>

#define TMAXV 100000
#define CHUNK 256
#define NCHUNK ((TMAXV + CHUNK - 1) / CHUNK)   // 391
#define WB 512                                  // bucket width in t
#define LOGWB 9
#define SB ((TMAXV + WB - 1) / WB)              // 196 buckets
#define SBP 256                                 // padded bucket count (scan width)
#define TILE 4096
#define RPT 16                                  // records per thread (TILE/256)
#define KS 8                                    // slices per bucket in hist phase
#define NREP 2                                  // LDS histogram replicas
#define HSCALE 4096.0f                          // fixed-point scale for h
#define HINV (1.0f / 4096.0f)
#define FUSZ (TILE + 640)                       // tile records + pad (<=3 per bucket)

// record encoding (32 bits): [31]=event  [30:9]=round(exp(x)*4096) (22-bit fixed
// point, clamped)  [8:0]=slot (t & 511). Abs quantization error <= 2^-13.
// Pad record = 0x00000000 (slot 0, hf 0, e 0): adds zero to every sum.
// All (tile,bucket) runs padded to multiples of 4 records -> every val store is
// an aligned uint4 (round 7 showed scatter is store-transaction-bound).

// ---------------- block reduce helpers (blockDim.x == 256) ----------------
__device__ __forceinline__ float block_reduce_sum(float v, float* sdata) {
    int lane = threadIdx.x & 63;
    int wid  = threadIdx.x >> 6;
    #pragma unroll
    for (int off = 32; off > 0; off >>= 1)
        v += __shfl_down(v, off, 64);
    if (lane == 0) sdata[wid] = v;
    __syncthreads();
    if (wid == 0) {
        v = (lane < 4) ? sdata[lane] : 0.0f;
        v += __shfl_down(v, 2, 64);
        v += __shfl_down(v, 1, 64);
    }
    return v;  // valid in thread 0
}

__device__ __forceinline__ double block_reduce_sum_d(double v, double* sdata) {
    int lane = threadIdx.x & 63;
    int wid  = threadIdx.x >> 6;
    #pragma unroll
    for (int off = 32; off > 0; off >>= 1)
        v += __shfl_down(v, off, 64);
    if (lane == 0) sdata[wid] = v;
    __syncthreads();
    if (wid == 0) {
        v = (lane < 4) ? sdata[lane] : 0.0;
        v += __shfl_down(v, 2, 64);
        v += __shfl_down(v, 1, 64);
    }
    return v;  // valid in thread 0
}

__device__ __forceinline__ unsigned encode_rec(float x, int t, int e) {
    float h = __expf(x);
    unsigned hf = (unsigned)__float2uint_rn(h * HSCALE);
    if (hf > 0x3FFFFFu) hf = 0x3FFFFFu;
    return (hf << 9)
         | (unsigned)(t & (WB - 1))
         | ((unsigned)e << 31);
}

// ================= FAST PATH =============================================

// ---- P1: per-tile counts PADDED to x4 + in-tile exclusive scan (tile-major);
//      also zeroes the accumulator region (replaces hipMemsetAsync dispatch)
__global__ void count_pfx_kernel(const int* __restrict__ tgt,
                                 int* __restrict__ pfx_arr,
                                 int* __restrict__ cnt_t,
                                 int* __restrict__ tot_t,
                                 unsigned* __restrict__ zero_base,
                                 int nzero_dw, int n) {
    __shared__ int lc[SBP];
    __shared__ int ls[SBP];
    int tid = threadIdx.x, tile = blockIdx.x;
    for (int i = tile * 256 + tid; i < nzero_dw; i += gridDim.x * 256)
        zero_base[i] = 0u;
    lc[tid] = 0;
    __syncthreads();
    int lo = tile * TILE;
    if (lo + TILE <= n) {
        const int4* tgt4 = (const int4*)(tgt + lo);
        #pragma unroll
        for (int q = 0; q < RPT / 4; ++q) {
            int4 t4 = tgt4[q * 256 + tid];
            atomicAdd(&lc[t4.x >> LOGWB], 1);
            atomicAdd(&lc[t4.y >> LOGWB], 1);
            atomicAdd(&lc[t4.z >> LOGWB], 1);
            atomicAdd(&lc[t4.w >> LOGWB], 1);
        }
    } else {
        int hi = min(n, lo + TILE);
        for (int i = lo + tid; i < hi; i += 256)
            atomicAdd(&lc[tgt[i] >> LOGWB], 1);
    }
    __syncthreads();
    int cp = (lc[tid] + 3) & ~3;           // pad run to multiple of 4 records
    ls[tid] = cp;
    __syncthreads();
    for (int off = 1; off < SBP; off <<= 1) {
        int a = (tid >= off) ? ls[tid - off] : 0;
        __syncthreads();
        ls[tid] += a;
        __syncthreads();
    }
    size_t rb = (size_t)tile * SBP;
    pfx_arr[rb + tid] = ls[tid] - cp;
    cnt_t[rb + tid] = cp;
    if (tid == 255) tot_t[tile] = ls[255];
}

// ---- P2: per-bucket scan over tiles (padded counts). 8 tiles/thread serial
//      prefix + ONE block scan per 2048 tiles. Last-done block performs the
//      bucket-base exclusive scan. Grid = SBP blocks.
__global__ void tile_scan_kernel(const int* __restrict__ cnt_t,
                                 int* __restrict__ tilebase_t,
                                 int* __restrict__ totals,
                                 int* __restrict__ base,
                                 unsigned* __restrict__ done,
                                 int nt, int n) {
    __shared__ int ls[256];
    __shared__ int lastFlag;
    int s = blockIdx.x, tid = threadIdx.x;
    int run = 0;
    for (int t0 = 0; t0 < nt; t0 += 256 * 8) {
        int c[8];
        #pragma unroll
        for (int u = 0; u < 8; ++u) {
            int t = t0 + tid * 8 + u;
            c[u] = (t < nt) ? cnt_t[(size_t)t * SBP + s] : 0;
        }
        int tot = 0;
        #pragma unroll
        for (int u = 0; u < 8; ++u) { int v = c[u]; c[u] = tot; tot += v; }
        ls[tid] = tot;
        __syncthreads();
        for (int off = 1; off < 256; off <<= 1) {
            int a = (tid >= off) ? ls[tid - off] : 0;
            __syncthreads();
            ls[tid] += a;
            __syncthreads();
        }
        int excl = ls[tid] - tot;
        int btot = ls[255];
        #pragma unroll
        for (int u = 0; u < 8; ++u) {
            int t = t0 + tid * 8 + u;
            if (t < nt) tilebase_t[(size_t)t * SBP + s] = run + excl + c[u];
        }
        run += btot;
        __syncthreads();
    }
    if (tid == 0) {
        __hip_atomic_store(&totals[s], run, __ATOMIC_RELEASE, __HIP_MEMORY_SCOPE_AGENT);
        unsigned prev = __hip_atomic_fetch_add(done, 1u, __ATOMIC_ACQ_REL, __HIP_MEMORY_SCOPE_AGENT);
        lastFlag = (prev == (unsigned)(gridDim.x - 1)) ? 1 : 0;
    }
    __syncthreads();
    if (lastFlag) {
        int c = __hip_atomic_load(&totals[tid], __ATOMIC_ACQUIRE, __HIP_MEMORY_SCOPE_AGENT);
        ls[tid] = c;
        __syncthreads();
        for (int off = 1; off < 256; off <<= 1) {
            int a = (tid >= off) ? ls[tid - off] : 0;
            __syncthreads();
            ls[tid] += a;
            __syncthreads();
        }
        base[tid] = ls[tid] - c;
        if (tid == 255) base[SBP] = ls[255];
    }
}

// ---- P3: streamed scatter with ALIGNED uint4 write-out (padded runs) ----
__global__ void scatter_kernel(const float* __restrict__ lh,
                               const int*   __restrict__ tgt,
                               const int*   __restrict__ ev,
                               const int*   __restrict__ pfx_arr,
                               const int*   __restrict__ tilebase_t,
                               const int*   __restrict__ base,
                               const int*   __restrict__ tot_t,
                               unsigned* __restrict__ val,
                               double* __restrict__ acc, int n, int nt) {
    __shared__ alignas(16) unsigned fu[FUSZ];   // 18.9 KB
    __shared__ unsigned char bidv[FUSZ];        // 4.7 KB
    __shared__ int pfx[SBP];                    // 1 KB
    __shared__ int tb[SBP];                     // 1 KB
    __shared__ int lrank[SBP];                  // 1 KB
    __shared__ int stot;
    __shared__ float sdata[4];
    int tid  = threadIdx.x;
    int tile = blockIdx.x;
    int lo   = tile * TILE;
    int cnt_here = min(TILE, n - lo);
    size_t rb = (size_t)tile * SBP;

    pfx[tid]   = pfx_arr[rb + tid];
    tb[tid]    = base[tid] + tilebase_t[rb + tid];
    lrank[tid] = 0;
    if (tid == 0) stot = tot_t[tile];
    __syncthreads();

    float xl = 0.f;
    if (lo + TILE <= n) {
        const int4*   tgt4 = (const int4*)(tgt + lo);
        const int4*   ev4  = (const int4*)(ev + lo);
        const float4* lh4  = (const float4*)(lh + lo);
        #pragma unroll
        for (int q = 0; q < RPT / 4; ++q) {
            int idx = q * 256 + tid;
            int4   t4 = tgt4[idx];
            int4   e4 = ev4[idx];
            float4 x4 = lh4[idx];
            {
                int b = t4.x >> LOGWB; unsigned r = encode_rec(x4.x, t4.x, e4.x & 1);
                int k = atomicAdd(&lrank[b], 1); int pos = pfx[b] + k;
                fu[pos] = r; bidv[pos] = (unsigned char)b; if (e4.x & 1) xl += x4.x;
            }
            {
                int b = t4.y >> LOGWB; unsigned r = encode_rec(x4.y, t4.y, e4.y & 1);
                int k = atomicAdd(&lrank[b], 1); int pos = pfx[b] + k;
                fu[pos] = r; bidv[pos] = (unsigned char)b; if (e4.y & 1) xl += x4.y;
            }
            {
                int b = t4.z >> LOGWB; unsigned r = encode_rec(x4.z, t4.z, e4.z & 1);
                int k = atomicAdd(&lrank[b], 1); int pos = pfx[b] + k;
                fu[pos] = r; bidv[pos] = (unsigned char)b; if (e4.z & 1) xl += x4.z;
            }
            {
                int b = t4.w >> LOGWB; unsigned r = encode_rec(x4.w, t4.w, e4.w & 1);
                int k = atomicAdd(&lrank[b], 1); int pos = pfx[b] + k;
                fu[pos] = r; bidv[pos] = (unsigned char)b; if (e4.w & 1) xl += x4.w;
            }
        }
    } else {
        for (int i = lo + tid; i < lo + cnt_here; i += 256) {
            int t = tgt[i]; int e = ev[i] & 1; float x = lh[i];
            int b = t >> LOGWB; unsigned r = encode_rec(x, t, e);
            int rr = atomicAdd(&lrank[b], 1); int pos = pfx[b] + rr;
            fu[pos] = r; bidv[pos] = (unsigned char)b; if (e) xl += x;
        }
    }
    __syncthreads();

    // fill pad slots (<=3 per bucket) with the zero record
    {
        int pb = pfx[tid] + lrank[tid];
        int pe = ((tid == 255) ? stot : pfx[tid + 1]);
        for (int p = pb; p < pe; ++p) fu[p] = 0u;
    }
    __syncthreads();

    // write-out: every 4-record group is single-bucket & 16B-aligned -> uint4
    int groups = stot >> 2;
    const uint4* fu4 = (const uint4*)fu;
    uint4* val4 = (uint4*)val;
    for (int g = tid; g < groups; g += 256) {
        uint4 bb = fu4[g];
        int p0 = g * 4;
        int b  = (int)bidv[p0];             // first of group is always real
        val4[(tb[b] + p0 - pfx[b]) >> 2] = bb;
    }

    float rl = block_reduce_sum(xl, sdata);
    if (tid == 0) unsafeAtomicAdd(&acc[2], (double)rl);   // native f64 atomic
}

// ---- P4: direct LDS histogram, INTEGER atomics only (ds_add_u32 native).
//      uint4 loads (regions & slices 4-aligned); pads add 0. Grid = SB*KS.
__global__ void bucket_hist_kernel(const unsigned* __restrict__ val,
                                   const int* __restrict__ base,
                                   unsigned* __restrict__ sh_g,
                                   unsigned* __restrict__ cm_g,
                                   unsigned* __restrict__ th_g,
                                   float* __restrict__ chunk_sum) {
    __shared__ unsigned shi[NREP][WB];   // 4 KB
    __shared__ unsigned cmi[NREP][WB];   // 4 KB
    __shared__ unsigned thi[NREP][WB];   // 4 KB
    __shared__ float sdata[4];
    __shared__ float sdata2[4];
    int tid = threadIdx.x;
    int rep = (tid >> 6) & (NREP - 1);   // wave parity picks replica
    int b   = blockIdx.x >> 3;           // KS == 8
    int k   = blockIdx.x & (KS - 1);
    int lo0 = base[b], len = base[b + 1] - lo0;
    int li  = lo0 + ((int)(((long long)len * k) / KS) & ~3);
    int hi  = lo0 + ((int)(((long long)len * (k + 1)) / KS) & ~3);

    #pragma unroll
    for (int u = 0; u < NREP * WB / 256; ++u) {
        ((unsigned*)shi)[u * 256 + tid] = 0u;
        ((unsigned*)cmi)[u * 256 + tid] = 0u;
        ((unsigned*)thi)[u * 256 + tid] = 0u;
    }
    __syncthreads();

    const uint4* v4 = (const uint4*)val;
#define HPROC(bits)                                                        \
    {                                                                      \
        unsigned _b = (bits);                                              \
        int      _s = (int)(_b & (WB - 1));                                \
        unsigned _h = (_b >> 9) & 0x3FFFFFu;                               \
        atomicAdd(&shi[rep][_s], _h);                                      \
        if (_b >> 31) { atomicAdd(&cmi[rep][_s], 1u);                      \
                        atomicAdd(&thi[rep][_s], _h); }                    \
    }
    for (int g = (li >> 2) + tid; g < (hi >> 2); g += 256) {
        uint4 w = v4[g];
        HPROC(w.x); HPROC(w.y); HPROC(w.z); HPROC(w.w);
    }
#undef HPROC
    __syncthreads();

    unsigned s0 = shi[0][tid]       + shi[1][tid];
    unsigned s1 = shi[0][tid + 256] + shi[1][tid + 256];
    unsigned c0 = cmi[0][tid]       + cmi[1][tid];
    unsigned c1 = cmi[0][tid + 256] + cmi[1][tid + 256];
    unsigned t0v = thi[0][tid]       + thi[1][tid];
    unsigned t1v = thi[0][tid + 256] + thi[1][tid + 256];

    int t0 = b * WB + tid;
    if (s0)  atomicAdd(&sh_g[t0],       s0);
    if (s1)  atomicAdd(&sh_g[t0 + 256], s1);
    if (c0)  atomicAdd(&cm_g[t0],       c0);
    if (c1)  atomicAdd(&cm_g[t0 + 256], c1);
    if (t0v) atomicAdd(&th_g[t0],       t0v);
    if (t1v) atomicAdd(&th_g[t0 + 256], t1v);

    float r0 = block_reduce_sum((float)s0 * HINV, sdata);
    __syncthreads();
    float r1 = block_reduce_sum((float)s1 * HINV, sdata2);
    if (tid == 0) {
        unsafeAtomicAdd(&chunk_sum[2 * b],     r0);   // native global f32 atomic
        unsafeAtomicAdd(&chunk_sum[2 * b + 1], r1);
    }
}

// ---- P5: per-chunk suffix + Efron; last-done block finalizes the output
__global__ void pll_suffix_kernel(const unsigned* __restrict__ sh_g,
                                  const unsigned* __restrict__ cm_g,
                                  const unsigned* __restrict__ th_g,
                                  const float* __restrict__ chunk_sum,
                                  double* __restrict__ acc,
                                  unsigned* __restrict__ done,
                                  float* __restrict__ out) {
    __shared__ float sf[CHUNK];
    __shared__ float sdata[4];
    __shared__ float sdata2[4];
    __shared__ double dsd[4];
    __shared__ double doff;
    int tid = threadIdx.x;
    int b   = blockIdx.x;
    int t   = b * CHUNK + tid;
    float sh = (float)sh_g[t] * HINV;
    unsigned cmu = cm_g[t];
    float th = (float)th_g[t] * HINV;
    sf[tid] = sh;
    __syncthreads();
    for (int off = 1; off < CHUNK; off <<= 1) {
        float add = (tid + off < CHUNK) ? sf[tid + off] : 0.0f;
        __syncthreads();
        sf[tid] += add;
        __syncthreads();
    }
    double mysum = 0.0;
    for (int j = b + 1 + tid; j < NCHUNK; j += 256)
        mysum += (double)chunk_sum[j];
    double red = block_reduce_sum_d(mysum, dsd);
    if (tid == 0) doff = red;
    __syncthreads();
    double off_d = doff;

    float pll = 0.0f, inc = 0.0f;
    if (t < TMAXV && cmu > 0u) {
        float cm   = (float)cmu;
        float D    = (float)(off_d + (double)sf[tid]);
        int   mi   = (int)cmu;
        float step = th / cm;
        float s = 0.0f;
        for (int l = 0; l < mi; ++l)
            s += __logf(D - (float)l * step);
        pll = -s;            // log_nom handled globally via acc[2]
        inc = 1.0f;
    }
    float rp = block_reduce_sum(pll, sdata);
    __syncthreads();
    float ri = block_reduce_sum(inc, sdata2);
    if (tid == 0) {
        unsafeAtomicAdd(&acc[0], (double)rp);
        unsafeAtomicAdd(&acc[1], (double)ri);
        __threadfence();
        unsigned prev = __hip_atomic_fetch_add(done, 1u, __ATOMIC_ACQ_REL, __HIP_MEMORY_SCOPE_AGENT);
        if (prev == (unsigned)(gridDim.x - 1)) {
            double a0 = __hip_atomic_load(&acc[0], __ATOMIC_ACQUIRE, __HIP_MEMORY_SCOPE_AGENT);
            double a1 = __hip_atomic_load(&acc[1], __ATOMIC_RELAXED, __HIP_MEMORY_SCOPE_AGENT);
            double a2 = __hip_atomic_load(&acc[2], __ATOMIC_RELAXED, __HIP_MEMORY_SCOPE_AGENT);
            out[0] = (a1 > 0.0) ? (float)(-(a0 + a2) / a1) : 0.0f;
        }
    }
}

// ---- finalize (fallback path only) ----
__global__ void finalize_kernel(const double* __restrict__ acc,
                                float* __restrict__ out) {
    double cnt = acc[1];
    out[0] = (cnt > 0.0) ? (float)(-(acc[0] + acc[2]) / cnt) : 0.0f;
}

// ================= FALLBACK: round-1 global-atomic histogram ==============
__global__ void hist_kernel(const float* __restrict__ lh,
                            const int*   __restrict__ tgt,
                            const int*   __restrict__ ev,
                            float* __restrict__ sum_hz,
                            float* __restrict__ mcnt,
                            float* __restrict__ log_nom,
                            float* __restrict__ ties,
                            int n) {
    int i = blockIdx.x * blockDim.x + threadIdx.x;
    if (i >= n) return;
    float x = lh[i];
    int   t = tgt[i];
    int   e = ev[i];
    float h = __expf(x);
    unsafeAtomicAdd(&sum_hz[t], h);
    if (e) {
        unsafeAtomicAdd(&mcnt[t], 1.0f);
        unsafeAtomicAdd(&log_nom[t], x);
        unsafeAtomicAdd(&ties[t], h);
    }
}

__global__ void chunk_sum_kernel(const float* __restrict__ sum_hz,
                                 float* __restrict__ chunk_sum) {
    __shared__ float sdata[4];
    int i = blockIdx.x * CHUNK + threadIdx.x;
    float v = (i < TMAXV) ? sum_hz[i] : 0.0f;
    v = block_reduce_sum(v, sdata);
    if (threadIdx.x == 0) chunk_sum[blockIdx.x] = v;
}

__global__ void chunk_scan_kernel(const float* __restrict__ chunk_sum,
                                  double* __restrict__ chunk_off) {
    __shared__ double ds[512];
    int tid = threadIdx.x;
    double own = (tid < NCHUNK) ? (double)chunk_sum[tid] : 0.0;
    ds[tid] = own;
    __syncthreads();
    for (int off = 1; off < 512; off <<= 1) {
        double add = (tid + off < 512) ? ds[tid + off] : 0.0;
        __syncthreads();
        ds[tid] += add;
        __syncthreads();
    }
    if (tid < NCHUNK) chunk_off[tid] = ds[tid] - own;
}

__global__ void pll_kernel(const float* __restrict__ mcnt,
                           const float* __restrict__ log_nom,
                           const float* __restrict__ ties,
                           const float* __restrict__ sum_hz,
                           const double* __restrict__ chunk_off,
                           double* __restrict__ acc) {
    __shared__ float sf[CHUNK];
    __shared__ float sdata[4];
    __shared__ float sdata2[4];
    int tid = threadIdx.x;
    int t   = blockIdx.x * CHUNK + tid;
    float v = (t < TMAXV) ? sum_hz[t] : 0.0f;
    sf[tid] = v;
    __syncthreads();
    for (int off = 1; off < CHUNK; off <<= 1) {
        float add = (tid + off < CHUNK) ? sf[tid + off] : 0.0f;
        __syncthreads();
        sf[tid] += add;
        __syncthreads();
    }
    float pll = 0.0f, inc = 0.0f;
    if (t < TMAXV) {
        float mv = mcnt[t];
        if (mv > 0.5f) {
            float D    = (float)(chunk_off[blockIdx.x] + (double)sf[tid]);
            float T    = ties[t];
            int   mi   = (int)(mv + 0.5f);
            float step = T / mv;
            float s = 0.0f;
            for (int l = 0; l < mi; ++l)
                s += __logf(D - (float)l * step);
            pll = log_nom[t] - s;
            inc = 1.0f;
        }
    }
    float rp = block_reduce_sum(pll, sdata);
    __syncthreads();
    float ri = block_reduce_sum(inc, sdata2);
    if (threadIdx.x == 0) {
        atomicAdd(&acc[0], (double)rp);
        atomicAdd(&acc[1], (double)ri);
    }
}

// =========================================================================
extern "C" void kernel_launch(void* const* d_in, const int* in_sizes, int n_in,
                              void* d_out, int out_size, void* d_ws, size_t ws_size,
                              hipStream_t stream) {
    const float* lh  = (const float*)d_in[0];
    const int*   tgt = (const int*)d_in[1];
    const int*   ev  = (const int*)d_in[2];
    float*       out = (float*)d_out;
    int n  = in_sizes[0];
    int nt = (n + TILE - 1) / TILE;   // number of tiles

    char* ws = (char*)d_ws;
    size_t off = 0;
    auto take = [&](size_t bytes, size_t align) {
        off = (off + align - 1) & ~(align - 1);
        size_t r = off; off += bytes; return r;
    };
    // ---- zero region (contiguous, zeroed by count_pfx grid-stride) ----
    size_t o_acc   = take(32, 16);                        // 3 doubles used
    size_t o_done  = take(16, 16);                        // done counters (scan, pll)
    size_t o_csum  = take((size_t)512 * 4, 16);           // chunk_sum (float)
    size_t o_shg   = take((size_t)SB * WB * 4, 16);       // per-t sum exp (u32 fx)
    size_t o_cmg   = take((size_t)SB * WB * 4, 16);       // per-t event count (u32)
    size_t o_thg   = take((size_t)SB * WB * 4, 16);       // per-t tie sum (u32 fx)
    size_t zero_bytes = off;                              // ~1.2 MB
    // ---- non-zeroed ----
    size_t o_base   = take((size_t)(SBP + 1) * 4, 16);
    size_t o_totals = take((size_t)SBP * 4, 16);
    size_t o_tot    = take((size_t)nt * 4, 16);           // per-tile padded totals
    size_t o_pfx    = take((size_t)nt * SBP * 4, 16);     // 2 MB
    size_t o_tbs    = take((size_t)nt * SBP * 4, 16);     // 2 MB
    // cnt_t (live P1-P2) overlays val (live P3-P4): both at o_val
    size_t o_val    = take((size_t)(n + 3 * (size_t)nt * SB + 64) * 4, 16); // ~38.3 MB
    size_t need     = off;

    if (ws_size >= need) {
        // ================= fast path =================
        double*   acc       = (double*)(ws + o_acc);
        unsigned* done      = (unsigned*)(ws + o_done);
        float*    chunk_sum = (float*)(ws + o_csum);
        unsigned* sh_g      = (unsigned*)(ws + o_shg);
        unsigned* cm_g      = (unsigned*)(ws + o_cmg);
        unsigned* th_g      = (unsigned*)(ws + o_thg);
        int*      base      = (int*)(ws + o_base);
        int*      totals    = (int*)(ws + o_totals);
        int*      tot_t     = (int*)(ws + o_tot);
        int*      pfx_arr   = (int*)(ws + o_pfx);
        int*      tilebase_t= (int*)(ws + o_tbs);
        int*      cnt_t     = (int*)(ws + o_val);         // overlay (dead after P2)
        unsigned* val       = (unsigned*)(ws + o_val);

        count_pfx_kernel<<<nt, 256, 0, stream>>>(tgt, pfx_arr, cnt_t, tot_t,
                                                 (unsigned*)ws, (int)(zero_bytes / 4), n);
        tile_scan_kernel<<<SBP, 256, 0, stream>>>(cnt_t, tilebase_t, totals, base,
                                                  done + 0, nt, n);
        scatter_kernel<<<nt, 256, 0, stream>>>(lh, tgt, ev, pfx_arr, tilebase_t, base,
                                               tot_t, val, acc, n, nt);
        bucket_hist_kernel<<<SB * KS, 256, 0, stream>>>(val, base, sh_g, cm_g, th_g,
                                                        chunk_sum);
        pll_suffix_kernel<<<NCHUNK, 256, 0, stream>>>(sh_g, cm_g, th_g, chunk_sum,
                                                      acc, done + 1, out);
    } else {
        // ================= fallback (round-1 style) =================
        size_t f = 0;
        auto ftake = [&](size_t bytes, size_t align) {
            f = (f + align - 1) & ~(align - 1);
            size_t r = f; f += bytes; return r;
        };
        size_t f_acc  = ftake(32, 16);
        size_t f_sum  = ftake((size_t)TMAXV * 4, 16);
        size_t f_m    = ftake((size_t)TMAXV * 4, 16);
        size_t f_ln   = ftake((size_t)TMAXV * 4, 16);
        size_t f_ties = ftake((size_t)TMAXV * 4, 16);
        size_t zb     = f;
        size_t f_csum = ftake((size_t)NCHUNK * 4, 16);
        size_t f_coff = ftake((size_t)NCHUNK * 8, 8);

        double* acc     = (double*)(ws + f_acc);
        float*  sum_hz  = (float*)(ws + f_sum);
        float*  mcnt    = (float*)(ws + f_m);
        float*  log_nom = (float*)(ws + f_ln);
        float*  ties    = (float*)(ws + f_ties);
        float*  chunk_sum = (float*)(ws + f_csum);
        double* chunk_off = (double*)(ws + f_coff);

        hipMemsetAsync(d_ws, 0, zb, stream);

        hist_kernel<<<(n + 255) / 256, 256, 0, stream>>>(lh, tgt, ev, sum_hz, mcnt, log_nom, ties, n);
        chunk_sum_kernel<<<NCHUNK, 256, 0, stream>>>(sum_hz, chunk_sum);
        chunk_scan_kernel<<<1, 512, 0, stream>>>(chunk_sum, chunk_off);
        pll_kernel<<<NCHUNK, 256, 0, stream>>>(mcnt, log_nom, ties, sum_hz, chunk_off, acc);
        finalize_kernel<<<1, 1, 0, stream>>>(acc, out);
    }
}